// Round 9
// baseline (75.762 us; speedup 1.0000x reference)
//
#include <hip/hip_runtime.h>

// SKAttention fused, MI355X — 4-kernel pipeline, Z-matvec fused into means.
// x,x1 (128,512,16,16) f32; fc_w (32,512); fc_b (32); fcs_w (2,512,32); fcs_b (2,512).
// Out: 2 x (128,512,12,16) f32 concat.
//
// attn0 = sigmoid(l0-l1). Group 0 dropped -> rows 0..3 dead. p = 4g+j, g in 1..3.
// out1[b,ch,4(g-1)+h,4j+w] = attn0(g,j,b,ch)*x[b,ch,4g+h,4j+w] + x[4g+j,ch,4g+h,4j+w]
// out2 same with x1, 1-attn0.
//
// Attribution (r1..r8): means=17, diag=1.5, out=26 (≈196MB floor), middle=30-34
// REGARDLESS of structure (gathered / transposed+3 kernels). Conclusion: the
// middle's cost is structural (S/Z round-trips, cold wprep, launch/drain), not
// access patterns. Fix: fuse Z-partials into means (P[g,b,j,q,d], 768 KB),
// kill wprep/z/S entirely.

#define BS 128
#define C  512
#define D  32
#define QCH 32

typedef float f32x4 __attribute__((ext_vector_type(4)));

// K1: diag extras -> E[src][ch*192 + (g-1)*64 + h*16 + j*4 + w] = src[4g+j][ch][4g+h][4j+w]
__global__ __launch_bounds__(256) void skatt_diag(
    const float* __restrict__ x, const float* __restrict__ x1,
    float* __restrict__ E)
{
    const int src = blockIdx.y;
    const float* in = src ? x1 : x;
    float* Eo = E + (size_t)src * (C * 192);

    const int flat = blockIdx.x * 256 + threadIdx.x;   // 0..24575 float4
    const int ch  = flat / 48;
    const int rem = flat - ch * 48;
    const int g   = (rem >> 4) + 1;
    const int h   = (rem >> 2) & 3;
    const int j   = rem & 3;

    const size_t src_ofs = (size_t)(4 * g + j) * (C * 256) + ch * 256 + (4 * g + h) * 16 + 4 * j;
    float4 v = *(const float4*)(in + src_ofs);
    *(float4*)(Eo + ch * 192 + rem * 4) = v;
}

// K2: patch means of (x+x1) + fused partial Z matvec.
// P[((g1*BS+b)*4 + j)*128 + q*32 + d] = sum_{c in q-chunk} mean[j][c] * fc_w[d][c]
__global__ __launch_bounds__(256) void skatt_meanz(
    const float* __restrict__ x, const float* __restrict__ x1,
    const float* __restrict__ fc_w,
    float* __restrict__ P)
{
    const int g = blockIdx.x + 1;
    const int b = blockIdx.y;
    const int q = blockIdx.z;
    const int t = threadIdx.x;
    const int j  = t & 3;
    const int cl = t >> 2;   // 0..63

    __shared__ float s_s[4][128];   // [j][c_local] means

    const size_t base = (size_t)b * (C * 256);
    #pragma unroll
    for (int i = 0; i < 2; ++i) {
        const int ch = q * 128 + cl + i * 64;
        const float* px = x  + base + ch * 256 + (4 * g) * 16 + j * 4;
        const float* p1 = x1 + base + ch * 256 + (4 * g) * 16 + j * 4;
        float s = 0.f;
        #pragma unroll
        for (int h = 0; h < 4; ++h) {
            float4 a  = *(const float4*)(px + h * 16);
            float4 c2 = *(const float4*)(p1 + h * 16);
            s += (a.x + c2.x) + (a.y + c2.y) + (a.z + c2.z) + (a.w + c2.w);
        }
        s_s[j][cl + i * 64] = s * (1.0f / 16.0f);
    }
    __syncthreads();

    // wave w handles j=w: partial Z over this block's 128 channels.
    const int w = t >> 6;   // 0..3
    const int l = t & 63;
    const float m0 = s_s[w][l];
    const float m1 = s_s[w][l + 64];
    const float* wrow = fc_w + q * 128 + l;   // lane-coalesced fc_w reads
    float* Pw = P + ((size_t)((g - 1) * BS + b) * 4 + w) * 128 + q * 32;

    #pragma unroll 4
    for (int d = 0; d < 32; ++d) {
        float v = m0 * wrow[d * C] + m1 * wrow[d * C + 64];
        #pragma unroll
        for (int s = 32; s > 0; s >>= 1)
            v += __shfl_xor(v, s, 64);
        if (l == 0) Pw[d] = v;
    }
}

// K3: attn0 = sigmoid(bd[ch] + Z[j][:] . Wd[ch][:]) -> A[g1][b][ch][j]
// Z = sum_q P + fc_b, staged in LDS. Wd/bd computed in-kernel (coalesced loads).
__global__ __launch_bounds__(256) void skatt_attn3(
    const float* __restrict__ P, const float* __restrict__ fc_b,
    const float* __restrict__ fcs_w, const float* __restrict__ fcs_b,
    float* __restrict__ A)
{
    const int qc = blockIdx.x;   // ch-chunk (16)
    const int qb = blockIdx.y;   // b-chunk (4)
    const int g1 = blockIdx.z;   // 3
    const int t  = threadIdx.x;
    const int ch0 = qc * 32, b0 = qb * 32;

    __shared__ float s_z[32 * 128];   // [b_l][j][d], 16 KB
    __shared__ float s_wt[32][32];    // [d][ch_l]
    __shared__ float s_bd[32];

    // stage Z = sum_q P + fc_b
    const f32x4* Pgb = (const f32x4*)(P + (size_t)(g1 * BS + b0) * 512);
    const f32x4* fb4 = (const f32x4*)fc_b;
    #pragma unroll
    for (int i = 0; i < 4; ++i) {
        const int v   = t + i * 256;     // 0..1023 = (b_l, j, d4)
        const int b_l = v >> 5;
        const int jj  = (v >> 3) & 3;
        const int d4  = v & 7;
        const int pb  = b_l * 128 + jj * 32 + d4;   // f4 units
        f32x4 acc = fb4[d4];
        #pragma unroll
        for (int qq = 0; qq < 4; ++qq) {
            f32x4 pv = Pgb[pb + qq * 8];
            acc.x += pv.x; acc.y += pv.y; acc.z += pv.z; acc.w += pv.w;
        }
        *(f32x4*)(s_z + (b_l * 32 + jj * 8 + d4) * 4) = acc;
    }
    // Wd = fcs_w0 - fcs_w1, transposed into LDS
    {
        const f32x4* w04 = (const f32x4*)(fcs_w + (size_t)ch0 * D);
        const f32x4* w14 = (const f32x4*)(fcs_w + (size_t)C * D + (size_t)ch0 * D);
        f32x4 a  = w04[t];
        f32x4 bb = w14[t];
        const int ch = t >> 3, d0 = (t & 7) * 4;
        s_wt[d0 + 0][ch] = a.x - bb.x;
        s_wt[d0 + 1][ch] = a.y - bb.y;
        s_wt[d0 + 2][ch] = a.z - bb.z;
        s_wt[d0 + 3][ch] = a.w - bb.w;
    }
    if (t < 32) s_bd[t] = fcs_b[ch0 + t] - fcs_b[C + ch0 + t];
    __syncthreads();

    const int ch_l = t & 31, bq = t >> 5;
    float wd[D];
    #pragma unroll
    for (int d = 0; d < D; ++d) wd[d] = s_wt[d][ch_l];
    const float bdv = s_bd[ch_l];

    #pragma unroll
    for (int bi = 0; bi < 4; ++bi) {
        const int b_l = bq + 8 * bi;
        const float* zr = s_z + b_l * 128;
        f32x4 o;
        #pragma unroll
        for (int j = 0; j < 4; ++j) {
            float acc = bdv;
            #pragma unroll
            for (int d = 0; d < D; ++d) acc += zr[j * 32 + d] * wd[d];
            o[j] = 1.0f / (1.0f + __expf(-acc));
        }
        *(f32x4*)(A + ((size_t)(g1 * BS + b0 + b_l) * C + ch0 + ch_l) * 4) = o;
    }
}

// K4: streaming elementwise output, NT stores.
__global__ __launch_bounds__(256) void skatt_out(
    const float* __restrict__ x, const float* __restrict__ x1,
    const float* __restrict__ E, const float* __restrict__ A,
    float* __restrict__ out)
{
    const int q = blockIdx.x;
    const int b = blockIdx.y;
    const int t = threadIdx.x;

    __shared__ float s_A[QCH][12];

    if (t < 96) {
        const int g1 = t >> 5, r = t & 31;
        float4 v = *(const float4*)(A + ((size_t)g1 * BS + b) * (C * 4) + q * (QCH * 4) + r * 4);
        *(float4*)(&s_A[r][g1 * 4]) = v;
    }
    __syncthreads();

    const size_t xbase = (size_t)b * (C * 256);
    const size_t obase = (size_t)b * (C * 192);
    const size_t out2_off = (size_t)BS * C * 192;
    const float* E1 = E;
    const float* E2 = E + (size_t)C * 192;

    #pragma unroll
    for (int i = 0; i < 6; ++i) {
        const int v    = t + i * 256;
        const int ch_l = v / 48;
        const int rem  = v - ch_l * 48;
        const int ch   = q * QCH + ch_l;
        const int j    = rem & 3;
        const int g1   = rem >> 4;

        const float at0 = s_A[ch_l][g1 * 4 + j];
        const float at1 = 1.0f - at0;

        const size_t xofs = xbase + ch * 256 + 64 + rem * 4;
        float4 a  = *(const float4*)(x  + xofs);
        float4 c2 = *(const float4*)(x1 + xofs);
        const size_t eofs = (size_t)ch * 192 + rem * 4;
        float4 e1 = *(const float4*)(E1 + eofs);
        float4 e2 = *(const float4*)(E2 + eofs);

        f32x4 r1, r2;
        r1.x = at0 * a.x + e1.x;   r2.x = at1 * c2.x + e2.x;
        r1.y = at0 * a.y + e1.y;   r2.y = at1 * c2.y + e2.y;
        r1.z = at0 * a.z + e1.z;   r2.z = at1 * c2.z + e2.z;
        r1.w = at0 * a.w + e1.w;   r2.w = at1 * c2.w + e2.w;

        const size_t oofs = obase + ch * 192 + rem * 4;
        __builtin_nontemporal_store(r1, (f32x4*)(out + oofs));
        __builtin_nontemporal_store(r2, (f32x4*)(out + out2_off + oofs));
    }
}

extern "C" void kernel_launch(void* const* d_in, const int* in_sizes, int n_in,
                              void* d_out, int out_size, void* d_ws, size_t ws_size,
                              hipStream_t stream) {
    const float* x     = (const float*)d_in[0];
    const float* x1    = (const float*)d_in[1];
    const float* fc_w  = (const float*)d_in[2];
    const float* fc_b  = (const float*)d_in[3];
    const float* fcs_w = (const float*)d_in[4];
    const float* fcs_b = (const float*)d_in[5];
    float* out = (float*)d_out;

    float* P = (float*)d_ws;            // 3*128*512 = 196608 f
    float* A = P + 196608;              // 786432 f
    float* E = A + 786432;              // 196608 f

    skatt_diag <<<dim3(96, 2),    256, 0, stream>>>(x, x1, E);
    skatt_meanz<<<dim3(3, BS, 4), 256, 0, stream>>>(x, x1, fc_w, P);
    skatt_attn3<<<dim3(16, 4, 3), 256, 0, stream>>>(P, fc_b, fcs_w, fcs_b, A);
    skatt_out  <<<dim3(16, BS),   256, 0, stream>>>(x, x1, E, A, out);
}

// Round 10
// 70.697 us; speedup vs baseline: 1.0717x; 1.0717x over previous
//
#include <hip/hip_runtime.h>

// SKAttention fused, MI355X — 3-kernel pipeline, attn fused into output kernel.
// x,x1 (128,512,16,16) f32; fc_w (32,512); fc_b (32); fcs_w (2,512,32); fcs_b (2,512).
// Out: 2 x (128,512,12,16) f32 concat.
//
// attn0 = sigmoid(l0-l1). Group 0 dropped -> rows 0..3 dead. p = 4g+j, g in 1..3.
// out1[b,ch,4(g-1)+h,4j+w] = attn0(g,j,b,ch)*x[b,ch,4g+h,4j+w] + x[4g+j,ch,4g+h,4j+w]
// out2 same with x1, 1-attn0.
//
// r5-r9 lesson: totals pinned at ~75us across 3 different middle structures;
// component math says the middle is NOT the cost. Isolating the one change
// present in all ~75us rounds: nontemporal stores in skatt_out. This round
// uses PLAIN stores (fills prove 7 TB/s plain-store BW) and fuses the tiny
// attn math into the out kernel (drops A round-trip + 1 launch).
//
// K1 diag : diag extras -> E (output-ordered), ~1.5MB traffic.
// K2 meanz: stream x+x1 rows 4..16 (96MB), patch means in LDS, fused partial
//           Z matvec (coalesced fc_w, shfl-reduce) -> P[g,b,j,q*32+d] (3MB).
// K3 outf : per (q=32ch, b): Z=sum_q P + fc_b (LDS), Wd from fcs_w (LDS,
//           transposed), attn sigmoid in-block, then streaming elementwise
//           output with plain float4 stores.

#define BS 128
#define C  512
#define D  32

typedef float f32x4 __attribute__((ext_vector_type(4)));

// K1: E[src][ch*192 + (g-1)*64 + h*16 + j*4 + w] = src[4g+j][ch][4g+h][4j+w]
__global__ __launch_bounds__(256) void skatt_diag(
    const float* __restrict__ x, const float* __restrict__ x1,
    float* __restrict__ E)
{
    const int src = blockIdx.y;
    const float* in = src ? x1 : x;
    float* Eo = E + (size_t)src * (C * 192);

    const int flat = blockIdx.x * 256 + threadIdx.x;   // 0..24575 float4
    const int ch  = flat / 48;
    const int rem = flat - ch * 48;
    const int g   = (rem >> 4) + 1;
    const int h   = (rem >> 2) & 3;
    const int j   = rem & 3;

    const size_t src_ofs = (size_t)(4 * g + j) * (C * 256) + ch * 256 + (4 * g + h) * 16 + 4 * j;
    float4 v = *(const float4*)(in + src_ofs);
    *(float4*)(Eo + ch * 192 + rem * 4) = v;
}

// K2: patch means of (x+x1) + fused partial Z matvec.
// P[((g1*BS+b)*4 + j)*128 + q*32 + d] = sum_{c in q-chunk} mean[j][c] * fc_w[d][c]
__global__ __launch_bounds__(256) void skatt_meanz(
    const float* __restrict__ x, const float* __restrict__ x1,
    const float* __restrict__ fc_w,
    float* __restrict__ P)
{
    const int g = blockIdx.x + 1;
    const int b = blockIdx.y;
    const int q = blockIdx.z;
    const int t = threadIdx.x;
    const int j  = t & 3;
    const int cl = t >> 2;   // 0..63

    __shared__ float s_s[4][128];   // [j][c_local] means

    const size_t base = (size_t)b * (C * 256);
    #pragma unroll
    for (int i = 0; i < 2; ++i) {
        const int ch = q * 128 + cl + i * 64;
        const float* px = x  + base + ch * 256 + (4 * g) * 16 + j * 4;
        const float* p1 = x1 + base + ch * 256 + (4 * g) * 16 + j * 4;
        float s = 0.f;
        #pragma unroll
        for (int h = 0; h < 4; ++h) {
            float4 a  = *(const float4*)(px + h * 16);
            float4 c2 = *(const float4*)(p1 + h * 16);
            s += (a.x + c2.x) + (a.y + c2.y) + (a.z + c2.z) + (a.w + c2.w);
        }
        s_s[j][cl + i * 64] = s * (1.0f / 16.0f);
    }
    __syncthreads();

    // wave w handles j=w: partial Z over this block's 128 channels.
    const int w = t >> 6;   // 0..3
    const int l = t & 63;
    const float m0 = s_s[w][l];
    const float m1 = s_s[w][l + 64];
    const float* wrow = fc_w + q * 128 + l;   // lane-coalesced fc_w reads
    float* Pw = P + ((size_t)((g - 1) * BS + b) * 4 + w) * 128 + q * 32;

    #pragma unroll 4
    for (int d = 0; d < 32; ++d) {
        float v = m0 * wrow[d * C] + m1 * wrow[d * C + 64];
        #pragma unroll
        for (int s = 32; s > 0; s >>= 1)
            v += __shfl_xor(v, s, 64);
        if (l == 0) Pw[d] = v;
    }
}

// K3: fused attn + streaming output. Grid (16 ch-chunks, 128 b), 256 threads.
__global__ __launch_bounds__(256) void skatt_outf(
    const float* __restrict__ x, const float* __restrict__ x1,
    const float* __restrict__ E, const float* __restrict__ P,
    const float* __restrict__ fc_b,
    const float* __restrict__ fcs_w, const float* __restrict__ fcs_b,
    float* __restrict__ out)
{
    const int q = blockIdx.x;      // 32-ch chunk
    const int b = blockIdx.y;
    const int t = threadIdx.x;
    const int ch0 = q * 32;

    __shared__ float s_z[3][128];    // [g1][j*32+d]
    __shared__ float s_wt[32][33];   // [d][ch_l], padded
    __shared__ float s_bd[32];
    __shared__ float s_A[32][12];    // [ch_l][g1*4+j]

    // Z = sum_q P + fc_b  (96 threads: g1 x j x d4)
    if (t < 96) {
        const int g1 = t >> 5, j = (t >> 3) & 3, d4 = t & 7;
        const f32x4* P4 = (const f32x4*)P;
        const size_t base4 = (size_t)(g1 * BS + b) * 128;
        f32x4 acc = ((const f32x4*)fc_b)[d4];
        #pragma unroll
        for (int qq = 0; qq < 4; ++qq) {
            f32x4 pv = P4[base4 + j * 32 + qq * 8 + d4];
            acc.x += pv.x; acc.y += pv.y; acc.z += pv.z; acc.w += pv.w;
        }
        *(f32x4*)(&s_z[g1][j * 32 + d4 * 4]) = acc;
    }
    // Wd = fcs_w0 - fcs_w1 transposed into LDS (all 256 threads)
    {
        const f32x4* w04 = (const f32x4*)(fcs_w + (size_t)ch0 * D);
        const f32x4* w14 = (const f32x4*)(fcs_w + (size_t)C * D + (size_t)ch0 * D);
        f32x4 a  = w04[t];
        f32x4 bb = w14[t];
        const int ch = t >> 3, d0 = (t & 7) * 4;
        s_wt[d0 + 0][ch] = a.x - bb.x;
        s_wt[d0 + 1][ch] = a.y - bb.y;
        s_wt[d0 + 2][ch] = a.z - bb.z;
        s_wt[d0 + 3][ch] = a.w - bb.w;
    }
    if (t < 32) s_bd[t] = fcs_b[ch0 + t] - fcs_b[C + ch0 + t];
    __syncthreads();

    // attn: 32ch x 12 (g,j) sigmoids over 256 threads (k = t>>5 handles p=k, p=k+8)
    {
        const int ch_l = t & 31, k = t >> 5;
        float wd[D];
        #pragma unroll
        for (int d = 0; d < D; ++d) wd[d] = s_wt[d][ch_l];
        const float bdv = s_bd[ch_l];

        {
            const int g1 = k >> 2, j = k & 3;
            float acc = bdv;
            #pragma unroll
            for (int d = 0; d < D; ++d) acc += s_z[g1][j * 32 + d] * wd[d];
            s_A[ch_l][k] = 1.0f / (1.0f + __expf(-acc));
        }
        if (k < 4) {
            const int p = k + 8;
            const int g1 = p >> 2, j = p & 3;
            float acc = bdv;
            #pragma unroll
            for (int d = 0; d < D; ++d) acc += s_z[g1][j * 32 + d] * wd[d];
            s_A[ch_l][p] = 1.0f / (1.0f + __expf(-acc));
        }
    }
    __syncthreads();

    // streaming elementwise output, plain float4 stores
    const size_t xbase = (size_t)b * (C * 256);
    const size_t obase = (size_t)b * (C * 192);
    const size_t out2_off = (size_t)BS * C * 192;
    const float* E1 = E;
    const float* E2 = E + (size_t)C * 192;

    #pragma unroll
    for (int i = 0; i < 6; ++i) {
        const int v    = t + i * 256;        // 0..1535 float4 index
        const int ch_l = v / 48;             // 0..31
        const int rem  = v - ch_l * 48;      // g1*16 + h*4 + j
        const int ch   = ch0 + ch_l;
        const int j    = rem & 3;
        const int g1   = rem >> 4;

        const float at0 = s_A[ch_l][g1 * 4 + j];
        const float at1 = 1.0f - at0;

        const size_t xofs = xbase + ch * 256 + 64 + rem * 4;
        float4 a  = *(const float4*)(x  + xofs);
        float4 c2 = *(const float4*)(x1 + xofs);
        const size_t eofs = (size_t)ch * 192 + rem * 4;
        float4 e1 = *(const float4*)(E1 + eofs);
        float4 e2 = *(const float4*)(E2 + eofs);

        float4 r1, r2;
        r1.x = at0 * a.x + e1.x;   r2.x = at1 * c2.x + e2.x;
        r1.y = at0 * a.y + e1.y;   r2.y = at1 * c2.y + e2.y;
        r1.z = at0 * a.z + e1.z;   r2.z = at1 * c2.z + e2.z;
        r1.w = at0 * a.w + e1.w;   r2.w = at1 * c2.w + e2.w;

        const size_t oofs = obase + ch * 192 + rem * 4;
        *(float4*)(out + oofs) = r1;
        *(float4*)(out + out2_off + oofs) = r2;
    }
}

extern "C" void kernel_launch(void* const* d_in, const int* in_sizes, int n_in,
                              void* d_out, int out_size, void* d_ws, size_t ws_size,
                              hipStream_t stream) {
    const float* x     = (const float*)d_in[0];
    const float* x1    = (const float*)d_in[1];
    const float* fc_w  = (const float*)d_in[2];
    const float* fc_b  = (const float*)d_in[3];
    const float* fcs_w = (const float*)d_in[4];
    const float* fcs_b = (const float*)d_in[5];
    float* out = (float*)d_out;

    float* P = (float*)d_ws;            // 3*128*4*128 = 196608 f
    float* E = P + 196608;              // 2*512*192   = 196608 f

    skatt_diag <<<dim3(96, 2),    256, 0, stream>>>(x, x1, E);
    skatt_meanz<<<dim3(3, BS, 4), 256, 0, stream>>>(x, x1, fc_w, P);
    skatt_outf <<<dim3(16, BS),   256, 0, stream>>>(x, x1, E, P, fc_b, fcs_w, fcs_b, out);
}

// Round 11
// 58.361 us; speedup vs baseline: 1.2982x; 1.2114x over previous
//
#include <hip/hip_runtime.h>

// SKAttention fused, MI355X — 3-kernel pipeline.
// x,x1 (128,512,16,16) f32; fc_w (32,512); fc_b (32); fcs_w (2,512,32); fcs_b (2,512).
// Out: 2 x (128,512,12,16) f32 concat.
//
// attn0 = sigmoid(l0-l1). Group 0 dropped -> rows 0..3 dead. p = 4g+j, g in 1..3.
// out1[b,ch,4(g-1)+h,4j+w] = attn0(g,j,b,ch)*x[b,ch,4g+h,4j+w] + x[4g+j,ch,4g+h,4j+w]
// out2 same with x1, 1-attn0.
//
// r10 profile: meanz=57us was the bottleneck — 192 dependent __shfl_xor per wave
// (DS-pipe latency chain), not the streaming loads. r2 proved the identical
// streaming phase alone is ~15us. Fix: replace shfl-reduce with LDS-staged
// weight slice + per-thread dot (zero cross-lane ops).
//
// K1 diag : diag extras -> E (output-ordered).
// K2 meanz: stream x+x1 rows 4..16 (96MB) -> means s_s[c][j] (2-way-free writes),
//           stage fc_w q-slice transposed s_w[c][d] (pad 33, conflict-free reads),
//           128 threads (j,d) do 128-iter broadcast*LDS dot -> P (coalesced).
// K3 outf : Z=sum_q P + fc_b, Wd from fcs_w, sigmoid, streaming output (plain f4).

#define BS 128
#define C  512
#define D  32

typedef float f32x4 __attribute__((ext_vector_type(4)));

// K1: E[src][ch*192 + (g-1)*64 + h*16 + j*4 + w] = src[4g+j][ch][4g+h][4j+w]
__global__ __launch_bounds__(256) void skatt_diag(
    const float* __restrict__ x, const float* __restrict__ x1,
    float* __restrict__ E)
{
    const int src = blockIdx.y;
    const float* in = src ? x1 : x;
    float* Eo = E + (size_t)src * (C * 192);

    const int flat = blockIdx.x * 256 + threadIdx.x;   // 0..24575 float4
    const int ch  = flat / 48;
    const int rem = flat - ch * 48;
    const int g   = (rem >> 4) + 1;
    const int h   = (rem >> 2) & 3;
    const int j   = rem & 3;

    const size_t src_ofs = (size_t)(4 * g + j) * (C * 256) + ch * 256 + (4 * g + h) * 16 + 4 * j;
    float4 v = *(const float4*)(in + src_ofs);
    *(float4*)(Eo + ch * 192 + rem * 4) = v;
}

// K2: patch means + partial Z matvec, no cross-lane ops.
// P[((g1*BS+b)*4 + j)*128 + q*32 + d] = sum_{c in q-chunk} mean[j][c] * fc_w[d][c]
__global__ __launch_bounds__(256) void skatt_meanz(
    const float* __restrict__ x, const float* __restrict__ x1,
    const float* __restrict__ fc_w,
    float* __restrict__ P)
{
    const int g = blockIdx.x + 1;
    const int b = blockIdx.y;
    const int q = blockIdx.z;
    const int t = threadIdx.x;

    __shared__ float s_s[128][4];    // [c_local][j] means (writes 2-way = free)
    __shared__ float s_w[128][33];   // [c_local][d] fc_w slice, pad -> read conflict-free

    // phase A: streaming means of (x+x1)
    {
        const int j  = t & 3;
        const int cl = t >> 2;   // 0..63
        const size_t base = (size_t)b * (C * 256);
        #pragma unroll
        for (int i = 0; i < 2; ++i) {
            const int ch = q * 128 + cl + i * 64;
            const float* px = x  + base + ch * 256 + (4 * g) * 16 + j * 4;
            const float* p1 = x1 + base + ch * 256 + (4 * g) * 16 + j * 4;
            float s = 0.f;
            #pragma unroll
            for (int h = 0; h < 4; ++h) {
                float4 a  = *(const float4*)(px + h * 16);
                float4 c2 = *(const float4*)(p1 + h * 16);
                s += (a.x + c2.x) + (a.y + c2.y) + (a.z + c2.z) + (a.w + c2.w);
            }
            s_s[cl + i * 64][j] = s * (1.0f / 16.0f);
        }
    }

    // phase A2: stage fc_w q-slice transposed (coalesced global reads)
    {
        const int d  = t >> 3;          // 0..31
        const int c4 = t & 7;           // 0..7
        const float* wsrc = fc_w + d * C + q * 128 + c4 * 16;
        #pragma unroll
        for (int k = 0; k < 4; ++k) {
            float4 v = *(const float4*)(wsrc + k * 4);
            const int c = c4 * 16 + k * 4;
            s_w[c + 0][d] = v.x;
            s_w[c + 1][d] = v.y;
            s_w[c + 2][d] = v.z;
            s_w[c + 3][d] = v.w;
        }
    }
    __syncthreads();

    // phase B: 128 threads (j,d), pure LDS dot (broadcast x conflict-free)
    if (t < 128) {
        const int j = t >> 5, d = t & 31;
        float a0 = 0.f, a1 = 0.f, a2 = 0.f, a3 = 0.f;
        #pragma unroll 8
        for (int c = 0; c < 128; c += 4) {
            a0 += s_s[c + 0][j] * s_w[c + 0][d];
            a1 += s_s[c + 1][j] * s_w[c + 1][d];
            a2 += s_s[c + 2][j] * s_w[c + 2][d];
            a3 += s_s[c + 3][j] * s_w[c + 3][d];
        }
        P[((size_t)((g - 1) * BS + b) * 4 + j) * 128 + q * 32 + d] =
            (a0 + a1) + (a2 + a3);
    }
}

// K3: fused attn + streaming output. Grid (16 ch-chunks, 128 b), 256 threads.
__global__ __launch_bounds__(256) void skatt_outf(
    const float* __restrict__ x, const float* __restrict__ x1,
    const float* __restrict__ E, const float* __restrict__ P,
    const float* __restrict__ fc_b,
    const float* __restrict__ fcs_w, const float* __restrict__ fcs_b,
    float* __restrict__ out)
{
    const int q = blockIdx.x;      // 32-ch chunk
    const int b = blockIdx.y;
    const int t = threadIdx.x;
    const int ch0 = q * 32;

    __shared__ float s_z[3][128];    // [g1][j*32+d]
    __shared__ float s_wt[32][33];   // [d][ch_l], padded
    __shared__ float s_bd[32];
    __shared__ float s_A[32][12];    // [ch_l][g1*4+j]

    // Z = sum_q P + fc_b  (96 threads: g1 x j x d4)
    if (t < 96) {
        const int g1 = t >> 5, j = (t >> 3) & 3, d4 = t & 7;
        const f32x4* P4 = (const f32x4*)P;
        const size_t base4 = (size_t)(g1 * BS + b) * 128;
        f32x4 acc = ((const f32x4*)fc_b)[d4];
        #pragma unroll
        for (int qq = 0; qq < 4; ++qq) {
            f32x4 pv = P4[base4 + j * 32 + qq * 8 + d4];
            acc.x += pv.x; acc.y += pv.y; acc.z += pv.z; acc.w += pv.w;
        }
        *(f32x4*)(&s_z[g1][j * 32 + d4 * 4]) = acc;
    }
    // Wd = fcs_w0 - fcs_w1 transposed into LDS (all 256 threads)
    {
        const f32x4* w04 = (const f32x4*)(fcs_w + (size_t)ch0 * D);
        const f32x4* w14 = (const f32x4*)(fcs_w + (size_t)C * D + (size_t)ch0 * D);
        f32x4 a  = w04[t];
        f32x4 bb = w14[t];
        const int ch = t >> 3, d0 = (t & 7) * 4;
        s_wt[d0 + 0][ch] = a.x - bb.x;
        s_wt[d0 + 1][ch] = a.y - bb.y;
        s_wt[d0 + 2][ch] = a.z - bb.z;
        s_wt[d0 + 3][ch] = a.w - bb.w;
    }
    if (t < 32) s_bd[t] = fcs_b[ch0 + t] - fcs_b[C + ch0 + t];
    __syncthreads();

    // attn: 32ch x 12 (g,j) sigmoids (k = t>>5 handles p=k and p=k+8)
    {
        const int ch_l = t & 31, k = t >> 5;
        float wd[D];
        #pragma unroll
        for (int d = 0; d < D; ++d) wd[d] = s_wt[d][ch_l];
        const float bdv = s_bd[ch_l];

        {
            const int g1 = k >> 2, j = k & 3;
            float acc = bdv;
            #pragma unroll
            for (int d = 0; d < D; ++d) acc += s_z[g1][j * 32 + d] * wd[d];
            s_A[ch_l][k] = 1.0f / (1.0f + __expf(-acc));
        }
        if (k < 4) {
            const int p = k + 8;
            const int g1 = p >> 2, j = p & 3;
            float acc = bdv;
            #pragma unroll
            for (int d = 0; d < D; ++d) acc += s_z[g1][j * 32 + d] * wd[d];
            s_A[ch_l][p] = 1.0f / (1.0f + __expf(-acc));
        }
    }
    __syncthreads();

    // streaming elementwise output, plain float4 stores
    const size_t xbase = (size_t)b * (C * 256);
    const size_t obase = (size_t)b * (C * 192);
    const size_t out2_off = (size_t)BS * C * 192;
    const float* E1 = E;
    const float* E2 = E + (size_t)C * 192;

    #pragma unroll
    for (int i = 0; i < 6; ++i) {
        const int v    = t + i * 256;        // 0..1535 float4 index
        const int ch_l = v / 48;             // 0..31
        const int rem  = v - ch_l * 48;      // g1*16 + h*4 + j
        const int ch   = ch0 + ch_l;
        const int j    = rem & 3;
        const int g1   = rem >> 4;

        const float at0 = s_A[ch_l][g1 * 4 + j];
        const float at1 = 1.0f - at0;

        const size_t xofs = xbase + ch * 256 + 64 + rem * 4;
        float4 a  = *(const float4*)(x  + xofs);
        float4 c2 = *(const float4*)(x1 + xofs);
        const size_t eofs = (size_t)ch * 192 + rem * 4;
        float4 e1 = *(const float4*)(E1 + eofs);
        float4 e2 = *(const float4*)(E2 + eofs);

        float4 r1, r2;
        r1.x = at0 * a.x + e1.x;   r2.x = at1 * c2.x + e2.x;
        r1.y = at0 * a.y + e1.y;   r2.y = at1 * c2.y + e2.y;
        r1.z = at0 * a.z + e1.z;   r2.z = at1 * c2.z + e2.z;
        r1.w = at0 * a.w + e1.w;   r2.w = at1 * c2.w + e2.w;

        const size_t oofs = obase + ch * 192 + rem * 4;
        *(float4*)(out + oofs) = r1;
        *(float4*)(out + out2_off + oofs) = r2;
    }
}

extern "C" void kernel_launch(void* const* d_in, const int* in_sizes, int n_in,
                              void* d_out, int out_size, void* d_ws, size_t ws_size,
                              hipStream_t stream) {
    const float* x     = (const float*)d_in[0];
    const float* x1    = (const float*)d_in[1];
    const float* fc_w  = (const float*)d_in[2];
    const float* fc_b  = (const float*)d_in[3];
    const float* fcs_w = (const float*)d_in[4];
    const float* fcs_b = (const float*)d_in[5];
    float* out = (float*)d_out;

    float* P = (float*)d_ws;            // 3*128*4*128 = 196608 f
    float* E = P + 196608;              // 2*512*192   = 196608 f

    skatt_diag <<<dim3(96, 2),    256, 0, stream>>>(x, x1, E);
    skatt_meanz<<<dim3(3, BS, 4), 256, 0, stream>>>(x, x1, fc_w, P);
    skatt_outf <<<dim3(16, BS),   256, 0, stream>>>(x, x1, E, P, fc_b, fcs_w, fcs_b, out);
}